// Round 17
// baseline (359.505 us; speedup 1.0000x reference)
//
#include <hip/hip_runtime.h>
#include <hip/hip_bf16.h>
#include <cmath>

#define TPB 256

typedef __attribute__((ext_vector_type(8))) short s16x8;
typedef __attribute__((ext_vector_type(4))) float f32x4;
typedef unsigned short ushortT;

constexpr long long PSTR = 8454272;   // 514*514*32 ushorts per padded image
constexpr int HW = 512 * 512;

static __device__ __forceinline__ short f2bf(float f) {
    union { __hip_bfloat16 h; short s; } u;
    u.h = __float2bfloat16(f);
    return u.s;
}
static __device__ __forceinline__ float bf2f(unsigned short u) {
    union { unsigned int i; float f; } v;
    v.i = ((unsigned int)u) << 16;
    return v.f;
}
static __device__ __forceinline__ unsigned int pack2(float a, float b) {
    return (unsigned int)(unsigned short)f2bf(a) | ((unsigned int)(unsigned short)f2bf(b) << 16);
}

// global->LDS DMA, 16B per lane; lds dest = wave-uniform base + lane*16
#define GLOAD_LDS16(gp, lp) \
    __builtin_amdgcn_global_load_lds((const __attribute__((address_space(1))) void*)(gp), \
                                     (__attribute__((address_space(3))) void*)(lp), 16, 0, 0)

// ---------------------------------------------------------------------------
// Weight pack body. slot stride 10240 shorts; bias fp32 @ short-offset 9216.
// ---------------------------------------------------------------------------
static __device__ void pack_body(const float* w, const float* bias, const float* theta,
                                 short* dst, int CO, int CI_src, int ci_off, int cog, int l)
{
    const int l15 = l & 15, sl = l >> 4;
    for (int t = 0; t < 9; ++t) {
        for (int mt = 0; mt < 2; ++mt) {
            const int co = cog * 32 + 16 * mt + l15;
            s16x8 p;
            #pragma unroll
            for (int i = 0; i < 8; ++i) {
                const int pci = 8 * sl + i;
                float val = 0.f;
                if (co < CO && pci >= ci_off && pci < ci_off + CI_src) {
                    const int ci = pci - ci_off;
                    val = w[((size_t)co * CI_src + ci) * 9 + t];
                    if (theta && t == 4) {
                        float s = 0.f;
                        for (int tt = 0; tt < 9; ++tt) s += w[((size_t)co * CI_src + ci) * 9 + tt];
                        val -= theta[0] * s;
                    }
                }
                p[i] = f2bf(val);
            }
            *(s16x8*)(dst + ((size_t)(t * 2 + mt) * 64 + l) * 8) = p;
        }
    }
    if (l < 32) {
        const int co = cog * 32 + l;
        ((float*)(dst + 9216))[l] = (bias && co < CO) ? bias[co] : 0.f;
    }
}

__global__ __launch_bounds__(64) void packall_k(
    const float* e1w, const float* e1b, const float* e2w, const float* e2b,
    const float* e3w, const float* e3b, const float* e4w, const float* e4b,
    const float* e5w, const float* e5b, const float* resw, const float* resb,
    const float* d1w, const float* d1b, const float* d2w, const float* d2b,
    const float* ctw, const float* ctb, const float* lfw, const float* lfb,
    short* wpack)
{
    const int s = blockIdx.x;
    const float *w, *b;
    int CO = 32, CI = 32, coff = 0, cog = 0;
    switch (s) {
        case 0: w = e1w; b = e1b; CI = 3; break;
        case 1: w = e2w; b = e2b; break;
        case 2: w = e3w; b = e3b; break;
        case 3: w = e4w; b = e4b; break;
        case 4: w = e5w; b = e5b; break;
        case 5: w = resw; b = resb; break;
        case 6: w = d1w; b = d1b; break;
        case 7: w = d2w; b = d2b; CO = 1; break;
        case 8: case 9: w = ctw; b = ctb; CO = 64; CI = 9; cog = s - 8; break;
        default: w = lfw; b = lfb; CO = 64; CI = 3; coff = 9; cog = s - 10; break;
    }
    pack_body(w, b, nullptr, wpack + (size_t)s * 10240, CO, CI, coff, cog, threadIdx.x);
}

// ---------------------------------------------------------------------------
// zero halo rings of 8 padded NHWC buffers (A2 z0..3, B2 z0..3)
// ---------------------------------------------------------------------------
__global__ __launch_bounds__(TPB) void zero_k(unsigned int* A2u, unsigned int* B2u)
{
    const int idx = blockIdx.x * TPB + threadIdx.x;
    if (idx >= 8 * 32832) return;
    const int q = idx / 32832, r = idx % 32832;
    unsigned int* P = (q < 4 ? A2u : B2u) + (size_t)(q & 3) * 4227136;
    const int RSU = 514 * 16;
    int off;
    if (r < 8224)       off = r;
    else if (r < 16448) off = 513 * RSU + (r - 8224);
    else if (r < 24640) { int u = r - 16448; off = (1 + (u >> 4)) * RSU + (u & 15); }
    else                { int u = r - 24640; off = (1 + (u >> 4)) * RSU + 513 * 16 + (u & 15); }
    P[off] = 0u;
}

// ---------------------------------------------------------------------------
// Fused DWT + ct + lf conv -> per-block channel partial sums (r13, unchanged)
// ---------------------------------------------------------------------------
__global__ __launch_bounds__(TPB) void ctlf_k(
    const float* __restrict__ x0p, const short* __restrict__ wpack8,
    float* __restrict__ part)
{
    constexpr int RSX = 66;
    constexpr int ROWB = RSX * 64;
    __shared__ s16x8 lds_t[6 * RSX * 4];
    __shared__ float s_red[4][32];
    char* sb = (char*)lds_t;

    const int z = blockIdx.z, cog = blockIdx.y;
    const int bid = blockIdx.x;
    const int x0 = (bid & 3) * 64, y0 = (bid >> 2) * 4;
    const int tid = threadIdx.x, lane = tid & 63, wv = tid >> 6;
    const int l15 = lane & 15, slot = lane >> 4;

    const short* wslot = wpack8 + (size_t)cog * 10240;
    const float* xz = x0p + (size_t)z * 3 * HW;

    s16x8 wf[9][2];
    #pragma unroll
    for (int t = 0; t < 9; ++t)
        #pragma unroll
        for (int mt = 0; mt < 2; ++mt)
            wf[t][mt] = *(const s16x8*)(wslot + ((size_t)(t * 2 + mt) * 64 + lane) * 8);

    #pragma unroll
    for (int j = 0; j < 2; ++j) {
        const int p = j * 256 + tid;
        if (p < 396) {
            const int row = p / 66, lx = p - row * 66;
            const int vs = (lx + (lx >> 2)) & 3;
            char* base = sb + (row * RSX + lx) * 64;
            const int sy = y0 + row - 1, sx = x0 + lx - 1;
            s16x8 pk0, pk1, zz;
            #pragma unroll
            for (int i = 0; i < 8; ++i) { pk0[i] = 0; pk1[i] = 0; zz[i] = 0; }
            if (sy >= 0 && sy < 256 && sx >= 0 && sx < 256) {
                #pragma unroll
                for (int c = 0; c < 3; ++c) {
                    const float* xp = xz + ((size_t)c * 512 + 2 * sy) * 512 + 2 * sx;
                    const float2 tp = *(const float2*)xp;
                    const float2 bt = *(const float2*)(xp + 512);
                    const float a = tp.x, b = tp.y, cc = bt.x, d = bt.y;
                    pk0[c]     = f2bf(0.5f * (a + b - cc - d));
                    pk0[3 + c] = f2bf(0.5f * (a - b + cc - d));
                    const float hh = 0.5f * (a - b - cc + d);
                    const float ll = 0.5f * (a + b + cc + d);
                    if (c < 2) pk0[6 + c] = f2bf(hh);
                    else       pk1[0]     = f2bf(hh);
                    pk1[1 + c] = f2bf(ll);
                }
            }
            *(s16x8*)(base + ((0 ^ vs) << 4)) = pk0;
            *(s16x8*)(base + ((1 ^ vs) << 4)) = pk1;
            *(s16x8*)(base + ((2 ^ vs) << 4)) = zz;
            *(s16x8*)(base + ((3 ^ vs) << 4)) = zz;
        }
    }
    __syncthreads();

    const int xw = 16 * wv;
    int roff[3];
    #pragma unroll
    for (int dx = 0; dx < 3; ++dx) {
        const int lx = xw + dx + l15;
        const int vs = (lx + (lx >> 2)) & 3;
        roff[dx] = lx * 64 + ((slot ^ vs) << 4);
    }
    const float* bptr = (const float*)(wslot + 9216);

    float ps[2][4];
    #pragma unroll
    for (int mt = 0; mt < 2; ++mt)
        #pragma unroll
        for (int reg = 0; reg < 4; ++reg) ps[mt][reg] = 0.f;

    #pragma unroll
    for (int r2 = 0; r2 < 4; r2 += 2) {
        f32x4 acc[2][2];
        #pragma unroll
        for (int a = 0; a < 2; ++a)
            #pragma unroll
            for (int b = 0; b < 2; ++b)
                #pragma unroll
                for (int e = 0; e < 4; ++e) acc[a][b][e] = 0.f;

        #pragma unroll
        for (int dy = 0; dy < 3; ++dy) {
            const int rb0 = (r2 + dy) * ROWB;
            #pragma unroll
            for (int dx = 0; dx < 3; ++dx) {
                const int tap = dy * 3 + dx;
                const s16x8 b0 = *(const s16x8*)(sb + rb0 + roff[dx]);
                const s16x8 b1 = *(const s16x8*)(sb + rb0 + ROWB + roff[dx]);
                #pragma unroll
                for (int mt = 0; mt < 2; ++mt) {
                    acc[0][mt] = __builtin_amdgcn_mfma_f32_16x16x32_bf16(wf[tap][mt], b0, acc[0][mt], 0, 0, 0);
                    acc[1][mt] = __builtin_amdgcn_mfma_f32_16x16x32_bf16(wf[tap][mt], b1, acc[1][mt], 0, 0, 0);
                }
            }
        }

        #pragma unroll
        for (int rr = 0; rr < 2; ++rr)
            #pragma unroll
            for (int mt = 0; mt < 2; ++mt)
                #pragma unroll
                for (int reg = 0; reg < 4; ++reg)
                    ps[mt][reg] += fmaxf(acc[rr][mt][reg] + bptr[16 * mt + 4 * slot + reg], 0.f);
    }

    #pragma unroll
    for (int mt = 0; mt < 2; ++mt)
        #pragma unroll
        for (int reg = 0; reg < 4; ++reg) {
            #pragma unroll
            for (int o = 1; o < 16; o <<= 1)
                ps[mt][reg] += __shfl_xor(ps[mt][reg], o, 64);
        }
    #pragma unroll
    for (int mt = 0; mt < 2; ++mt)
        #pragma unroll
        for (int reg = 0; reg < 4; ++reg)
            if (l15 == mt * 4 + reg)
                s_red[wv][16 * mt + 4 * slot + reg] = ps[mt][reg];
    __syncthreads();
    if (tid < 32) {
        const float s = s_red[0][tid] + s_red[1][tid] + s_red[2][tid] + s_red[3][tid];
        part[(((size_t)z * 4 + cog) * 256 + bid) * 32 + tid] = s;
    }
}

// ---------------------------------------------------------------------------
// Fused scalar chain, one block per batch z:
// means -> tchain -> theta -> fc1/fc2/fc3 (LDS) -> gamma/beta -> cdc pack.
// ---------------------------------------------------------------------------
__global__ __launch_bounds__(TPB) void chainz_k(
    const float* __restrict__ part,
    const float* t1w, const float* t1b, const float* t2w, const float* t2b,
    const float* t3w, const float* t3b,
    const float* fc1w, const float* fc1b, const float* fc2w, const float* fc2b,
    const float* fc3w, const float* fc3b,
    const float* gw, const float* gbias, const float* bw, const float* bbias,
    const float* cdcw,
    float* __restrict__ gamma, float* __restrict__ beta, short* __restrict__ wpackcdc)
{
    const int z = blockIdx.x, tid = threadIdx.x;
    __shared__ float amean[64], am0s[64], a1[64], a2[64];
    __shared__ float am1[512], am2[512], am3[512];
    __shared__ float th;

    // channel means from ctlf partials (ct: cog 0,1 -> amean; lf: cog 2,3 -> am0s)
    if (tid < 128) {
        const int br = tid >> 6, co = tid & 63;
        const int cog = (br ? 2 : 0) + (co >> 5), c = co & 31;
        const float* p = part + (((size_t)z * 4 + cog) * 256) * 32 + c;
        float s = 0.f;
        for (int j = 0; j < 256; ++j) s += p[j * 32];
        (br ? am0s : amean)[co] = s * (1.f / 65536.f);
    }
    __syncthreads();

    // t1 + fc1
    if (tid < 64) {
        float s = t1b[tid];
        for (int ci = 0; ci < 64; ++ci) s = fmaf(t1w[tid * 64 + ci], amean[ci], s);
        a1[tid] = fmaxf(s, 0.f);
    }
    for (int o = tid; o < 512; o += TPB) {
        float s = fc1b[o];
        for (int ci = 0; ci < 64; ++ci) s = fmaf(fc1w[(size_t)o * 64 + ci], am0s[ci], s);
        am1[o] = fmaxf(s, 0.f);
    }
    __syncthreads();

    // t2 + fc2
    if (tid < 64) {
        float s = t2b[tid];
        for (int ci = 0; ci < 64; ++ci) s = fmaf(t2w[tid * 64 + ci], a1[ci], s);
        a2[tid] = fmaxf(s, 0.f);
    }
    for (int o = tid; o < 512; o += TPB) {
        float s = fc2b[o];
        for (int ci = 0; ci < 512; ++ci) s = fmaf(fc2w[(size_t)o * 512 + ci], am1[ci], s);
        am2[o] = fmaxf(s, 0.f);
    }
    __syncthreads();

    // theta + fc3
    if (tid == 0) {
        float v = t3b[0];
        for (int ci = 0; ci < 64; ++ci) v = fmaf(t3w[ci], a2[ci], v);
        th = 1.f / (1.f + expf(-v));
    }
    for (int o = tid; o < 512; o += TPB) {
        float s = fc3b[o];
        for (int ci = 0; ci < 512; ++ci) s = fmaf(fc3w[(size_t)o * 512 + ci], am2[ci], s);
        am3[o] = 1.f / (1.f + expf(-s));
    }
    __syncthreads();

    // gamma/beta heads (threads 0..63) + cdc pack (threads 64..127)
    if (tid < 64) {
        const int which = tid >> 5, co = tid & 31;
        const float* w  = which ? bw : gw;
        const float* bi = which ? bbias : gbias;
        float s = bi[co];
        for (int ci = 0; ci < 512; ++ci) s = fmaf(w[(size_t)co * 512 + ci], am3[ci], s);
        if (which) beta[z * 32 + co] = tanhf(s);
        else       gamma[z * 32 + co] = 1.f / (1.f + expf(-s));
    } else if (tid < 128) {
        pack_body(cdcw, nullptr, &th, wpackcdc + (size_t)z * 10240, 32, 32, 0, 0, tid - 64);
    }
}

// ---------------------------------------------------------------------------
// enc1: narrow 64px x 4row conv, fp32 NCHW 3-ch input -> padded NHWC bf16.
// ---------------------------------------------------------------------------
__global__ __launch_bounds__(TPB) void enc1n_k(
    const float* __restrict__ x0p, const short* __restrict__ wslot,
    ushortT* __restrict__ outP0)
{
    constexpr int RSX = 66;
    constexpr int ROWB = RSX * 64;
    __shared__ s16x8 lds_t[6 * RSX * 4];
    char* sb = (char*)lds_t;

    const int z = blockIdx.z;
    const float* xin = x0p + (size_t)z * 3 * HW;

    const int tid = threadIdx.x, lane = tid & 63, wv = tid >> 6;
    const int bid = blockIdx.x;
    const int swz = (bid & 7) * 128 + (bid >> 3);
    const int x0 = (swz & 7) * 64, y0 = (swz >> 3) * 4;
    const int l15 = lane & 15, slot = lane >> 4;

    s16x8 wf[9][2];
    #pragma unroll
    for (int t = 0; t < 9; ++t)
        #pragma unroll
        for (int mt = 0; mt < 2; ++mt)
            wf[t][mt] = *(const s16x8*)(wslot + ((size_t)(t * 2 + mt) * 64 + lane) * 8);

    #pragma unroll
    for (int j = 0; j < 2; ++j) {
        const int p = j * 256 + tid;
        if (p < 396) {
            const int row = p / 66, lx = p - row * 66;
            const int vs = (lx + (lx >> 2)) & 3;
            char* base = sb + (row * RSX + lx) * 64;
            const int gy = y0 + row - 1, gx = x0 + lx - 1;
            s16x8 pk, zz;
            #pragma unroll
            for (int i = 0; i < 8; ++i) { pk[i] = 0; zz[i] = 0; }
            if (gy >= 0 && gy < 512 && gx >= 0 && gx < 512) {
                #pragma unroll
                for (int c = 0; c < 3; ++c)
                    pk[c] = f2bf(xin[((size_t)c * 512 + gy) * 512 + gx]);
            }
            *(s16x8*)(base + ((0 ^ vs) << 4)) = pk;
            *(s16x8*)(base + ((1 ^ vs) << 4)) = zz;
            *(s16x8*)(base + ((2 ^ vs) << 4)) = zz;
            *(s16x8*)(base + ((3 ^ vs) << 4)) = zz;
        }
    }
    __syncthreads();

    const int xw = 16 * wv;
    int roff[3];
    #pragma unroll
    for (int dx = 0; dx < 3; ++dx) {
        const int lx = xw + dx + l15;
        const int vs = (lx + (lx >> 2)) & 3;
        roff[dx] = lx * 64 + ((slot ^ vs) << 4);
    }
    const float* bptr = (const float*)(wslot + 9216);
    ushortT* outP = outP0 + (size_t)z * PSTR;

    #pragma unroll
    for (int r2 = 0; r2 < 4; r2 += 2) {
        f32x4 acc[2][2];
        #pragma unroll
        for (int a = 0; a < 2; ++a)
            #pragma unroll
            for (int b = 0; b < 2; ++b)
                #pragma unroll
                for (int e = 0; e < 4; ++e) acc[a][b][e] = 0.f;

        #pragma unroll
        for (int dy = 0; dy < 3; ++dy) {
            const int rb0 = (r2 + dy) * ROWB;
            #pragma unroll
            for (int dx = 0; dx < 3; ++dx) {
                const int tap = dy * 3 + dx;
                const s16x8 b0 = *(const s16x8*)(sb + rb0 + roff[dx]);
                const s16x8 b1 = *(const s16x8*)(sb + rb0 + ROWB + roff[dx]);
                #pragma unroll
                for (int mt = 0; mt < 2; ++mt) {
                    acc[0][mt] = __builtin_amdgcn_mfma_f32_16x16x32_bf16(wf[tap][mt], b0, acc[0][mt], 0, 0, 0);
                    acc[1][mt] = __builtin_amdgcn_mfma_f32_16x16x32_bf16(wf[tap][mt], b1, acc[1][mt], 0, 0, 0);
                }
            }
        }

        #pragma unroll
        for (int rr = 0; rr < 2; ++rr) {
            const int gy = y0 + r2 + rr;
            const int gx = x0 + xw + l15;
            #pragma unroll
            for (int mt = 0; mt < 2; ++mt) {
                const size_t off = ((size_t)(gy + 1) * 514 + gx + 1) * 32 + 16 * mt + 4 * slot;
                float v[4];
                #pragma unroll
                for (int reg = 0; reg < 4; ++reg)
                    v[reg] = fmaxf(acc[rr][mt][reg] + bptr[16 * mt + 4 * slot + reg], 0.f);
                *(uint2*)(outP + off) = make_uint2(pack2(v[0], v[1]), pack2(v[2], v[3]));
            }
        }
    }
}

// ---------------------------------------------------------------------------
// Pipelined double-buffered DMA conv on padded NHWC bf16 (8 tiles/block).
// ---------------------------------------------------------------------------
template<int EPI>
__global__ __launch_bounds__(TPB) void dconv64p_k(
    const ushortT* __restrict__ inP0, const short* __restrict__ wbase, int wstr,
    ushortT* __restrict__ outP0,
    const float* __restrict__ gamma0, const float* __restrict__ beta0,
    const float* __restrict__ xorig0, float* __restrict__ outE0, float* __restrict__ outM0)
{
    constexpr int MT = (EPI == 3) ? 1 : 2;
    constexpr int RSX = 66;
    constexpr int ROWB = RSX * 64;
    constexpr int BUFB = 6 * RSX * 64;
    __shared__ s16x8 lds_t[2 * 6 * RSX * 4];
    char* sbase = (char*)lds_t;

    const int z = blockIdx.z;
    const ushortT* inP = inP0 + (size_t)z * PSTR;
    const short* wslot = wbase + (size_t)z * wstr;

    const int tid = threadIdx.x, lane = tid & 63, wv = tid >> 6;
    const int bid = blockIdx.x;                 // 0..127
    const int xcd = bid & 7, idx = bid >> 3;    // idx 0..15
    const int x0 = (idx & 7) * 64;
    const int yband = xcd * 2 + (idx >> 3);     // 0..15, 32 rows each
    const int l15 = lane & 15, slot = lane >> 4;

    s16x8 wf[9][MT];
    #pragma unroll
    for (int t = 0; t < 9; ++t)
        #pragma unroll
        for (int mt = 0; mt < MT; ++mt)
            wf[t][mt] = *(const s16x8*)(wslot + ((size_t)(t * 2 + mt) * 64 + lane) * 8);

    const int xw = 16 * wv;
    int roff[3];
    #pragma unroll
    for (int dx = 0; dx < 3; ++dx) {
        const int lx = xw + dx + l15;
        const int vs = (lx + (lx >> 2)) & 3;
        roff[dx] = lx * 64 + ((slot ^ vs) << 4);
    }
    const float* bptr = (const float*)(wslot + 9216);

    auto stage = [&](int t, int b) {
        const int y0 = yband * 32 + 4 * t;
        char* sb = sbase + b * BUFB;
        #pragma unroll
        for (int j = 0; j < 6; ++j) {
            const int p = j * 256 + tid;
            const int row = p / 264;
            const int rem = p - row * 264;
            const int lx = rem >> 2, osl = rem & 3;
            const int o = osl ^ ((lx + (lx >> 2)) & 3);
            const ushortT* gp = inP + ((size_t)(y0 + row) * 514 + x0 + lx) * 32 + o * 8;
            GLOAD_LDS16(gp, sb + (size_t)(j * 256 + wv * 64) * 16);
        }
        if (tid < 48) {
            const int p = 1536 + tid;
            const int row = p / 264;
            const int rem = p - row * 264;
            const int lx = rem >> 2, osl = rem & 3;
            const int o = osl ^ ((lx + (lx >> 2)) & 3);
            const ushortT* gp = inP + ((size_t)(y0 + row) * 514 + x0 + lx) * 32 + o * 8;
            GLOAD_LDS16(gp, sb + (size_t)1536 * 16);
        }
    };

    stage(0, 0);

    #pragma unroll 1
    for (int t = 0; t < 8; ++t) {
        __syncthreads();
        if (t < 7) stage(t + 1, (t + 1) & 1);
        char* sb = sbase + (t & 1) * BUFB;
        const int y0t = yband * 32 + 4 * t;

        #pragma unroll
        for (int r2 = 0; r2 < 4; r2 += 2) {
            f32x4 acc[2][MT];
            #pragma unroll
            for (int a = 0; a < 2; ++a)
                #pragma unroll
                for (int b = 0; b < MT; ++b)
                    #pragma unroll
                    for (int e = 0; e < 4; ++e) acc[a][b][e] = 0.f;

            #pragma unroll
            for (int dy = 0; dy < 3; ++dy) {
                const int rb0 = (r2 + dy) * ROWB;
                #pragma unroll
                for (int dx = 0; dx < 3; ++dx) {
                    const int tap = dy * 3 + dx;
                    const s16x8 b0 = *(const s16x8*)(sb + rb0 + roff[dx]);
                    const s16x8 b1 = *(const s16x8*)(sb + rb0 + ROWB + roff[dx]);
                    #pragma unroll
                    for (int mt = 0; mt < MT; ++mt) {
                        acc[0][mt] = __builtin_amdgcn_mfma_f32_16x16x32_bf16(wf[tap][mt], b0, acc[0][mt], 0, 0, 0);
                        acc[1][mt] = __builtin_amdgcn_mfma_f32_16x16x32_bf16(wf[tap][mt], b1, acc[1][mt], 0, 0, 0);
                    }
                }
            }

            #pragma unroll
            for (int rr = 0; rr < 2; ++rr) {
                const int gy = y0t + r2 + rr;
                const int gx = x0 + xw + l15;
                if constexpr (EPI == 3) {
                    if (slot == 0) {
                        const float* xorig = xorig0 + (size_t)z * 3 * HW;
                        float* outE = outE0 + (size_t)z * 3 * HW;
                        float* outM = outM0 + (size_t)z * HW;
                        const float om = tanhf(acc[rr][0][0] + bptr[0]);
                        outM[(size_t)gy * 512 + gx] = om;
                        #pragma unroll
                        for (int c = 0; c < 3; ++c) {
                            const size_t xi = ((size_t)c * 512 + gy) * 512 + gx;
                            const float xv = xorig[xi];
                            outE[xi] = xv + om * (xv * xv - xv);
                        }
                    }
                } else {
                    ushortT* outP = outP0 + (size_t)z * PSTR;
                    #pragma unroll
                    for (int mt = 0; mt < MT; ++mt) {
                        const size_t off = ((size_t)(gy + 1) * 514 + gx + 1) * 32 + 16 * mt + 4 * slot;
                        float v[4];
                        #pragma unroll
                        for (int reg = 0; reg < 4; ++reg)
                            v[reg] = acc[rr][mt][reg] + bptr[16 * mt + 4 * slot + reg];
                        if constexpr (EPI == 0) {
                            #pragma unroll
                            for (int reg = 0; reg < 4; ++reg) v[reg] = fmaxf(v[reg], 0.f);
                        } else if constexpr (EPI == 2) {
                            const int prow = r2 + rr + 1;
                            const int lxr = xw + l15 + 1;
                            const int vsr = (lxr + (lxr >> 2)) & 3;
                            const int oo = (2 * mt + (slot >> 1)) ^ vsr;
                            const uint2 din = *(const uint2*)(sb + (prow * RSX + lxr) * 64 + (oo << 4) + ((slot & 1) << 3));
                            const float* gamma = gamma0 + 32 * z;
                            const float* beta  = beta0 + 32 * z;
                            const int cb = 16 * mt + 4 * slot;
                            v[0] = bf2f((unsigned short)(din.x & 0xffff)) + gamma[cb + 0] * v[0] + beta[cb + 0];
                            v[1] = bf2f((unsigned short)(din.x >> 16))    + gamma[cb + 1] * v[1] + beta[cb + 1];
                            v[2] = bf2f((unsigned short)(din.y & 0xffff)) + gamma[cb + 2] * v[2] + beta[cb + 2];
                            v[3] = bf2f((unsigned short)(din.y >> 16))    + gamma[cb + 3] * v[3] + beta[cb + 3];
                        }
                        *(uint2*)(outP + off) = make_uint2(pack2(v[0], v[1]), pack2(v[2], v[3]));
                    }
                }
            }
        }
    }
}

// ---------------------------------------------------------------------------
extern "C" void kernel_launch(void* const* d_in, const int* in_sizes, int n_in,
                              void* d_out, int out_size, void* d_ws, size_t ws_size,
                              hipStream_t stream)
{
    const float* x      = (const float*)d_in[0];
    const float* cdc_w  = (const float*)d_in[11];
    const float* t1_w   = (const float*)d_in[14];
    const float* t1_b   = (const float*)d_in[15];
    const float* t2_w   = (const float*)d_in[16];
    const float* t2_b   = (const float*)d_in[17];
    const float* t3_w   = (const float*)d_in[18];
    const float* t3_b   = (const float*)d_in[19];
    const float* fc1_w  = (const float*)d_in[22];
    const float* fc1_b  = (const float*)d_in[23];
    const float* fc2_w  = (const float*)d_in[24];
    const float* fc2_b  = (const float*)d_in[25];
    const float* fc3_w  = (const float*)d_in[26];
    const float* fc3_b  = (const float*)d_in[27];
    const float* g_w    = (const float*)d_in[28];
    const float* g_b    = (const float*)d_in[29];
    const float* be_w   = (const float*)d_in[30];
    const float* be_b   = (const float*)d_in[31];

    float* out = (float*)d_out;

    // workspace layout
    ushortT* A2 = (ushortT*)d_ws;                  // 4 x 16.9 MB
    ushortT* B2 = A2 + 4 * PSTR;                   // 4 x 16.9 MB
    float* part  = (float*)(B2 + 4 * PSTR);        // 131072
    float* gamma = part + 131072;                  // 128 [4][32]
    float* beta  = gamma + 128;                    // 128
    short* wpack = (short*)(beta + 128);           // 16 x 10240 shorts
    const size_t need_bytes = (size_t)((char*)(wpack + 16 * 10240) - (char*)d_ws);
    if (ws_size < need_bytes) return;

    const dim3 blk(TPB);

    // --- phase A ---
    packall_k<<<dim3(12), dim3(64), 0, stream>>>(
        (const float*)d_in[1], (const float*)d_in[2], (const float*)d_in[3], (const float*)d_in[4],
        (const float*)d_in[5], (const float*)d_in[6], (const float*)d_in[7], (const float*)d_in[8],
        (const float*)d_in[9], (const float*)d_in[10], (const float*)d_in[32], (const float*)d_in[33],
        (const float*)d_in[34], (const float*)d_in[35], (const float*)d_in[36], (const float*)d_in[37],
        (const float*)d_in[12], (const float*)d_in[13], (const float*)d_in[20], (const float*)d_in[21],
        wpack);

    zero_k<<<dim3((8 * 32832 + TPB - 1) / TPB), blk, 0, stream>>>((unsigned int*)A2, (unsigned int*)B2);

    ctlf_k<<<dim3(256, 4, 4), blk, 0, stream>>>(x, wpack + 8 * 10240, part);

    // fused scalar chain: means -> tchain -> fc chain -> gamma/beta -> cdc pack
    chainz_k<<<dim3(4), blk, 0, stream>>>(part,
        t1_w, t1_b, t2_w, t2_b, t3_w, t3_b,
        fc1_w, fc1_b, fc2_w, fc2_b, fc3_w, fc3_b,
        g_w, g_b, be_w, be_b, cdc_w,
        gamma, beta, wpack + 12 * 10240);

    // --- heavy chain: enc1n + 8 pipelined dconv64p dispatches (8 tiles/blk) ---
    const dim3 gE(1024, 1, 4);
    const dim3 gP(128, 1, 4);
    float* outM = out + (size_t)4 * 3 * HW;

    enc1n_k<<<gE, blk, 0, stream>>>(x, wpack, A2);
    dconv64p_k<0><<<gP, blk, 0, stream>>>(A2, wpack + 1 * 10240, 0, B2, nullptr, nullptr, nullptr, nullptr, nullptr);
    dconv64p_k<0><<<gP, blk, 0, stream>>>(B2, wpack + 2 * 10240, 0, A2, nullptr, nullptr, nullptr, nullptr, nullptr);
    dconv64p_k<0><<<gP, blk, 0, stream>>>(A2, wpack + 3 * 10240, 0, B2, nullptr, nullptr, nullptr, nullptr, nullptr);
    dconv64p_k<0><<<gP, blk, 0, stream>>>(B2, wpack + 4 * 10240, 0, A2, nullptr, nullptr, nullptr, nullptr, nullptr);
    // cdc (theta folded per batch): A2 -> B2 = f_deco
    dconv64p_k<0><<<gP, blk, 0, stream>>>(A2, wpack + 12 * 10240, 10240, B2, nullptr, nullptr, nullptr, nullptr, nullptr);
    // res: B2 -> A2 (residual from LDS)
    dconv64p_k<2><<<gP, blk, 0, stream>>>(B2, wpack + 5 * 10240, 0, A2, gamma, beta, nullptr, nullptr, nullptr);
    // d1: A2 -> B2
    dconv64p_k<0><<<gP, blk, 0, stream>>>(A2, wpack + 6 * 10240, 0, B2, nullptr, nullptr, nullptr, nullptr, nullptr);
    // d2 + tanh + enhance -> outputs
    dconv64p_k<3><<<gP, blk, 0, stream>>>(B2, wpack + 7 * 10240, 0, nullptr, nullptr, nullptr, x, out, outM);
}

// Round 18
// 322.494 us; speedup vs baseline: 1.1148x; 1.1148x over previous
//
#include <hip/hip_runtime.h>
#include <hip/hip_bf16.h>
#include <cmath>

#define TPB 256

typedef __attribute__((ext_vector_type(8))) short s16x8;
typedef __attribute__((ext_vector_type(4))) float f32x4;
typedef unsigned short ushortT;

constexpr long long PSTR = 8454272;   // 514*514*32 ushorts per padded image
constexpr int HW = 512 * 512;

static __device__ __forceinline__ short f2bf(float f) {
    union { __hip_bfloat16 h; short s; } u;
    u.h = __float2bfloat16(f);
    return u.s;
}
static __device__ __forceinline__ float bf2f(unsigned short u) {
    union { unsigned int i; float f; } v;
    v.i = ((unsigned int)u) << 16;
    return v.f;
}
static __device__ __forceinline__ unsigned int pack2(float a, float b) {
    return (unsigned int)(unsigned short)f2bf(a) | ((unsigned int)(unsigned short)f2bf(b) << 16);
}

// global->LDS DMA, 16B per lane; lds dest = wave-uniform base + lane*16
#define GLOAD_LDS16(gp, lp) \
    __builtin_amdgcn_global_load_lds((const __attribute__((address_space(1))) void*)(gp), \
                                     (__attribute__((address_space(3))) void*)(lp), 16, 0, 0)

// ---------------------------------------------------------------------------
// Weight pack body. slot stride 10240 shorts; bias fp32 @ short-offset 9216.
// ---------------------------------------------------------------------------
static __device__ void pack_body(const float* w, const float* bias, const float* theta,
                                 short* dst, int CO, int CI_src, int ci_off, int cog, int l)
{
    const int l15 = l & 15, sl = l >> 4;
    for (int t = 0; t < 9; ++t) {
        for (int mt = 0; mt < 2; ++mt) {
            const int co = cog * 32 + 16 * mt + l15;
            s16x8 p;
            #pragma unroll
            for (int i = 0; i < 8; ++i) {
                const int pci = 8 * sl + i;
                float val = 0.f;
                if (co < CO && pci >= ci_off && pci < ci_off + CI_src) {
                    const int ci = pci - ci_off;
                    val = w[((size_t)co * CI_src + ci) * 9 + t];
                    if (theta && t == 4) {
                        float s = 0.f;
                        for (int tt = 0; tt < 9; ++tt) s += w[((size_t)co * CI_src + ci) * 9 + tt];
                        val -= theta[0] * s;
                    }
                }
                p[i] = f2bf(val);
            }
            *(s16x8*)(dst + ((size_t)(t * 2 + mt) * 64 + l) * 8) = p;
        }
    }
    if (l < 32) {
        const int co = cog * 32 + l;
        ((float*)(dst + 9216))[l] = (bias && co < CO) ? bias[co] : 0.f;
    }
}

__global__ __launch_bounds__(64) void packall_k(
    const float* e1w, const float* e1b, const float* e2w, const float* e2b,
    const float* e3w, const float* e3b, const float* e4w, const float* e4b,
    const float* e5w, const float* e5b, const float* resw, const float* resb,
    const float* d1w, const float* d1b, const float* d2w, const float* d2b,
    const float* ctw, const float* ctb, const float* lfw, const float* lfb,
    short* wpack)
{
    const int s = blockIdx.x;
    const float *w, *b;
    int CO = 32, CI = 32, coff = 0, cog = 0;
    switch (s) {
        case 0: w = e1w; b = e1b; CI = 3; break;
        case 1: w = e2w; b = e2b; break;
        case 2: w = e3w; b = e3b; break;
        case 3: w = e4w; b = e4b; break;
        case 4: w = e5w; b = e5b; break;
        case 5: w = resw; b = resb; break;
        case 6: w = d1w; b = d1b; break;
        case 7: w = d2w; b = d2b; CO = 1; break;
        case 8: case 9: w = ctw; b = ctb; CO = 64; CI = 9; cog = s - 8; break;
        default: w = lfw; b = lfb; CO = 64; CI = 3; coff = 9; cog = s - 10; break;
    }
    pack_body(w, b, nullptr, wpack + (size_t)s * 10240, CO, CI, coff, cog, threadIdx.x);
}

__global__ __launch_bounds__(64) void packcdc_k(
    const float* cdcw, const float* theta, short* wpack)
{
    const int b = blockIdx.x;
    pack_body(cdcw, nullptr, theta + b, wpack + (size_t)(12 + b) * 10240, 32, 32, 0, 0, threadIdx.x);
}

// ---------------------------------------------------------------------------
// zero halo rings of 8 padded NHWC buffers (A2 z0..3, B2 z0..3)
// ---------------------------------------------------------------------------
__global__ __launch_bounds__(TPB) void zero_k(unsigned int* A2u, unsigned int* B2u)
{
    const int idx = blockIdx.x * TPB + threadIdx.x;
    if (idx >= 8 * 32832) return;
    const int q = idx / 32832, r = idx % 32832;
    unsigned int* P = (q < 4 ? A2u : B2u) + (size_t)(q & 3) * 4227136;
    const int RSU = 514 * 16;
    int off;
    if (r < 8224)       off = r;
    else if (r < 16448) off = 513 * RSU + (r - 8224);
    else if (r < 24640) { int u = r - 16448; off = (1 + (u >> 4)) * RSU + (u & 15); }
    else                { int u = r - 24640; off = (1 + (u >> 4)) * RSU + 513 * 16 + (u & 15); }
    P[off] = 0u;
}

// ---------------------------------------------------------------------------
// Fused DWT + ct + lf conv -> per-block channel partial sums (r13, unchanged)
// ---------------------------------------------------------------------------
__global__ __launch_bounds__(TPB) void ctlf_k(
    const float* __restrict__ x0p, const short* __restrict__ wpack8,
    float* __restrict__ part)
{
    constexpr int RSX = 66;
    constexpr int ROWB = RSX * 64;
    __shared__ s16x8 lds_t[6 * RSX * 4];
    __shared__ float s_red[4][32];
    char* sb = (char*)lds_t;

    const int z = blockIdx.z, cog = blockIdx.y;
    const int bid = blockIdx.x;
    const int x0 = (bid & 3) * 64, y0 = (bid >> 2) * 4;
    const int tid = threadIdx.x, lane = tid & 63, wv = tid >> 6;
    const int l15 = lane & 15, slot = lane >> 4;

    const short* wslot = wpack8 + (size_t)cog * 10240;
    const float* xz = x0p + (size_t)z * 3 * HW;

    s16x8 wf[9][2];
    #pragma unroll
    for (int t = 0; t < 9; ++t)
        #pragma unroll
        for (int mt = 0; mt < 2; ++mt)
            wf[t][mt] = *(const s16x8*)(wslot + ((size_t)(t * 2 + mt) * 64 + lane) * 8);

    #pragma unroll
    for (int j = 0; j < 2; ++j) {
        const int p = j * 256 + tid;
        if (p < 396) {
            const int row = p / 66, lx = p - row * 66;
            const int vs = (lx + (lx >> 2)) & 3;
            char* base = sb + (row * RSX + lx) * 64;
            const int sy = y0 + row - 1, sx = x0 + lx - 1;
            s16x8 pk0, pk1, zz;
            #pragma unroll
            for (int i = 0; i < 8; ++i) { pk0[i] = 0; pk1[i] = 0; zz[i] = 0; }
            if (sy >= 0 && sy < 256 && sx >= 0 && sx < 256) {
                #pragma unroll
                for (int c = 0; c < 3; ++c) {
                    const float* xp = xz + ((size_t)c * 512 + 2 * sy) * 512 + 2 * sx;
                    const float2 tp = *(const float2*)xp;
                    const float2 bt = *(const float2*)(xp + 512);
                    const float a = tp.x, b = tp.y, cc = bt.x, d = bt.y;
                    pk0[c]     = f2bf(0.5f * (a + b - cc - d));
                    pk0[3 + c] = f2bf(0.5f * (a - b + cc - d));
                    const float hh = 0.5f * (a - b - cc + d);
                    const float ll = 0.5f * (a + b + cc + d);
                    if (c < 2) pk0[6 + c] = f2bf(hh);
                    else       pk1[0]     = f2bf(hh);
                    pk1[1 + c] = f2bf(ll);
                }
            }
            *(s16x8*)(base + ((0 ^ vs) << 4)) = pk0;
            *(s16x8*)(base + ((1 ^ vs) << 4)) = pk1;
            *(s16x8*)(base + ((2 ^ vs) << 4)) = zz;
            *(s16x8*)(base + ((3 ^ vs) << 4)) = zz;
        }
    }
    __syncthreads();

    const int xw = 16 * wv;
    int roff[3];
    #pragma unroll
    for (int dx = 0; dx < 3; ++dx) {
        const int lx = xw + dx + l15;
        const int vs = (lx + (lx >> 2)) & 3;
        roff[dx] = lx * 64 + ((slot ^ vs) << 4);
    }
    const float* bptr = (const float*)(wslot + 9216);

    float ps[2][4];
    #pragma unroll
    for (int mt = 0; mt < 2; ++mt)
        #pragma unroll
        for (int reg = 0; reg < 4; ++reg) ps[mt][reg] = 0.f;

    #pragma unroll
    for (int r2 = 0; r2 < 4; r2 += 2) {
        f32x4 acc[2][2];
        #pragma unroll
        for (int a = 0; a < 2; ++a)
            #pragma unroll
            for (int b = 0; b < 2; ++b)
                #pragma unroll
                for (int e = 0; e < 4; ++e) acc[a][b][e] = 0.f;

        #pragma unroll
        for (int dy = 0; dy < 3; ++dy) {
            const int rb0 = (r2 + dy) * ROWB;
            #pragma unroll
            for (int dx = 0; dx < 3; ++dx) {
                const int tap = dy * 3 + dx;
                const s16x8 b0 = *(const s16x8*)(sb + rb0 + roff[dx]);
                const s16x8 b1 = *(const s16x8*)(sb + rb0 + ROWB + roff[dx]);
                #pragma unroll
                for (int mt = 0; mt < 2; ++mt) {
                    acc[0][mt] = __builtin_amdgcn_mfma_f32_16x16x32_bf16(wf[tap][mt], b0, acc[0][mt], 0, 0, 0);
                    acc[1][mt] = __builtin_amdgcn_mfma_f32_16x16x32_bf16(wf[tap][mt], b1, acc[1][mt], 0, 0, 0);
                }
            }
        }

        #pragma unroll
        for (int rr = 0; rr < 2; ++rr)
            #pragma unroll
            for (int mt = 0; mt < 2; ++mt)
                #pragma unroll
                for (int reg = 0; reg < 4; ++reg)
                    ps[mt][reg] += fmaxf(acc[rr][mt][reg] + bptr[16 * mt + 4 * slot + reg], 0.f);
    }

    #pragma unroll
    for (int mt = 0; mt < 2; ++mt)
        #pragma unroll
        for (int reg = 0; reg < 4; ++reg) {
            #pragma unroll
            for (int o = 1; o < 16; o <<= 1)
                ps[mt][reg] += __shfl_xor(ps[mt][reg], o, 64);
        }
    #pragma unroll
    for (int mt = 0; mt < 2; ++mt)
        #pragma unroll
        for (int reg = 0; reg < 4; ++reg)
            if (l15 == mt * 4 + reg)
                s_red[wv][16 * mt + 4 * slot + reg] = ps[mt][reg];
    __syncthreads();
    if (tid < 32) {
        const float s = s_red[0][tid] + s_red[1][tid] + s_red[2][tid] + s_red[3][tid];
        part[(((size_t)z * 4 + cog) * 256 + bid) * 32 + tid] = s;
    }
}

// ---------------------------------------------------------------------------
// Fused means + t-chain, one block per batch z. Writes am0 (for fc1) and theta.
// ---------------------------------------------------------------------------
__global__ __launch_bounds__(TPB) void meantch_k(
    const float* __restrict__ part,
    const float* t1w, const float* t1b, const float* t2w, const float* t2b,
    const float* t3w, const float* t3b,
    float* __restrict__ am0, float* __restrict__ theta)
{
    const int z = blockIdx.x, tid = threadIdx.x;
    __shared__ float amean[64], a1[64], a2[64];

    if (tid < 128) {
        const int br = tid >> 6, co = tid & 63;
        const int cog = (br ? 2 : 0) + (co >> 5), c = co & 31;
        const float* p = part + (((size_t)z * 4 + cog) * 256) * 32 + c;
        float s = 0.f;
        for (int j = 0; j < 256; ++j) s += p[j * 32];
        const float m = s * (1.f / 65536.f);
        if (br) am0[z * 64 + co] = m;
        else    amean[co] = m;
    }
    __syncthreads();
    if (tid < 64) {
        float s = t1b[tid];
        #pragma unroll 8
        for (int ci = 0; ci < 64; ++ci) s = fmaf(t1w[tid * 64 + ci], amean[ci], s);
        a1[tid] = fmaxf(s, 0.f);
    }
    __syncthreads();
    if (tid < 64) {
        float s = t2b[tid];
        #pragma unroll 8
        for (int ci = 0; ci < 64; ++ci) s = fmaf(t2w[tid * 64 + ci], a1[ci], s);
        a2[tid] = fmaxf(s, 0.f);
    }
    __syncthreads();
    if (tid == 0) {
        float v = t3b[0];
        for (int ci = 0; ci < 64; ++ci) v = fmaf(t3w[ci], a2[ci], v);
        theta[z] = 1.f / (1.f + expf(-v));
    }
}

// ---------------------------------------------------------------------------
// wave-per-output FC. ACT 0 relu, 1 sigmoid, 2 tanh.
// ---------------------------------------------------------------------------
template<int ACT>
__global__ __launch_bounds__(TPB) void fcw_k(
    const float* __restrict__ in, const float* __restrict__ w,
    const float* __restrict__ bias, float* __restrict__ out, int K, int N)
{
    const int lane = threadIdx.x & 63, wv = threadIdx.x >> 6;
    const int idx = blockIdx.x * 4 + wv;
    if (idx >= 4 * N) return;
    const int b = idx / N, co = idx % N;
    float s = 0.f;
    for (int k = lane * 4; k < K; k += 256) {
        const float4 wv4 = *(const float4*)(w + (size_t)co * K + k);
        const float4 iv  = *(const float4*)(in + (size_t)b * K + k);
        s += wv4.x * iv.x + wv4.y * iv.y + wv4.z * iv.z + wv4.w * iv.w;
    }
    #pragma unroll
    for (int o = 32; o > 0; o >>= 1) s += __shfl_xor(s, o, 64);
    if (lane == 0) {
        s += bias[co];
        if (ACT == 0) s = fmaxf(s, 0.f);
        else if (ACT == 1) s = 1.f / (1.f + expf(-s));
        else s = tanhf(s);
        out[(size_t)b * N + co] = s;
    }
}

// ---------------------------------------------------------------------------
// gamma/beta heads in one launch: 256 outputs = 2 heads x 4z x 32co, wave each.
// ---------------------------------------------------------------------------
__global__ __launch_bounds__(TPB) void gb_k(
    const float* __restrict__ am3,
    const float* __restrict__ gw, const float* __restrict__ gbias,
    const float* __restrict__ bw, const float* __restrict__ bbias,
    float* __restrict__ gamma, float* __restrict__ beta)
{
    const int lane = threadIdx.x & 63, wv = threadIdx.x >> 6;
    const int idx = blockIdx.x * 4 + wv;          // 0..255
    if (idx >= 256) return;
    const int which = idx >> 7, rem = idx & 127;
    const int z = rem >> 5, co = rem & 31;
    const float* w = which ? bw : gw;
    float s = 0.f;
    for (int k = lane * 4; k < 512; k += 256) {
        const float4 wv4 = *(const float4*)(w + (size_t)co * 512 + k);
        const float4 iv  = *(const float4*)(am3 + (size_t)z * 512 + k);
        s += wv4.x * iv.x + wv4.y * iv.y + wv4.z * iv.z + wv4.w * iv.w;
    }
    #pragma unroll
    for (int o = 32; o > 0; o >>= 1) s += __shfl_xor(s, o, 64);
    if (lane == 0) {
        if (which) beta[z * 32 + co] = tanhf(s + bbias[co]);
        else       gamma[z * 32 + co] = 1.f / (1.f + expf(-(s + gbias[co])));
    }
}

// ---------------------------------------------------------------------------
// enc1: narrow 64px x 4row conv, fp32 NCHW 3-ch input -> padded NHWC bf16.
// ---------------------------------------------------------------------------
__global__ __launch_bounds__(TPB) void enc1n_k(
    const float* __restrict__ x0p, const short* __restrict__ wslot,
    ushortT* __restrict__ outP0)
{
    constexpr int RSX = 66;
    constexpr int ROWB = RSX * 64;
    __shared__ s16x8 lds_t[6 * RSX * 4];
    char* sb = (char*)lds_t;

    const int z = blockIdx.z;
    const float* xin = x0p + (size_t)z * 3 * HW;

    const int tid = threadIdx.x, lane = tid & 63, wv = tid >> 6;
    const int bid = blockIdx.x;
    const int swz = (bid & 7) * 128 + (bid >> 3);
    const int x0 = (swz & 7) * 64, y0 = (swz >> 3) * 4;
    const int l15 = lane & 15, slot = lane >> 4;

    s16x8 wf[9][2];
    #pragma unroll
    for (int t = 0; t < 9; ++t)
        #pragma unroll
        for (int mt = 0; mt < 2; ++mt)
            wf[t][mt] = *(const s16x8*)(wslot + ((size_t)(t * 2 + mt) * 64 + lane) * 8);

    #pragma unroll
    for (int j = 0; j < 2; ++j) {
        const int p = j * 256 + tid;
        if (p < 396) {
            const int row = p / 66, lx = p - row * 66;
            const int vs = (lx + (lx >> 2)) & 3;
            char* base = sb + (row * RSX + lx) * 64;
            const int gy = y0 + row - 1, gx = x0 + lx - 1;
            s16x8 pk, zz;
            #pragma unroll
            for (int i = 0; i < 8; ++i) { pk[i] = 0; zz[i] = 0; }
            if (gy >= 0 && gy < 512 && gx >= 0 && gx < 512) {
                #pragma unroll
                for (int c = 0; c < 3; ++c)
                    pk[c] = f2bf(xin[((size_t)c * 512 + gy) * 512 + gx]);
            }
            *(s16x8*)(base + ((0 ^ vs) << 4)) = pk;
            *(s16x8*)(base + ((1 ^ vs) << 4)) = zz;
            *(s16x8*)(base + ((2 ^ vs) << 4)) = zz;
            *(s16x8*)(base + ((3 ^ vs) << 4)) = zz;
        }
    }
    __syncthreads();

    const int xw = 16 * wv;
    int roff[3];
    #pragma unroll
    for (int dx = 0; dx < 3; ++dx) {
        const int lx = xw + dx + l15;
        const int vs = (lx + (lx >> 2)) & 3;
        roff[dx] = lx * 64 + ((slot ^ vs) << 4);
    }
    const float* bptr = (const float*)(wslot + 9216);
    ushortT* outP = outP0 + (size_t)z * PSTR;

    #pragma unroll
    for (int r2 = 0; r2 < 4; r2 += 2) {
        f32x4 acc[2][2];
        #pragma unroll
        for (int a = 0; a < 2; ++a)
            #pragma unroll
            for (int b = 0; b < 2; ++b)
                #pragma unroll
                for (int e = 0; e < 4; ++e) acc[a][b][e] = 0.f;

        #pragma unroll
        for (int dy = 0; dy < 3; ++dy) {
            const int rb0 = (r2 + dy) * ROWB;
            #pragma unroll
            for (int dx = 0; dx < 3; ++dx) {
                const int tap = dy * 3 + dx;
                const s16x8 b0 = *(const s16x8*)(sb + rb0 + roff[dx]);
                const s16x8 b1 = *(const s16x8*)(sb + rb0 + ROWB + roff[dx]);
                #pragma unroll
                for (int mt = 0; mt < 2; ++mt) {
                    acc[0][mt] = __builtin_amdgcn_mfma_f32_16x16x32_bf16(wf[tap][mt], b0, acc[0][mt], 0, 0, 0);
                    acc[1][mt] = __builtin_amdgcn_mfma_f32_16x16x32_bf16(wf[tap][mt], b1, acc[1][mt], 0, 0, 0);
                }
            }
        }

        #pragma unroll
        for (int rr = 0; rr < 2; ++rr) {
            const int gy = y0 + r2 + rr;
            const int gx = x0 + xw + l15;
            #pragma unroll
            for (int mt = 0; mt < 2; ++mt) {
                const size_t off = ((size_t)(gy + 1) * 514 + gx + 1) * 32 + 16 * mt + 4 * slot;
                float v[4];
                #pragma unroll
                for (int reg = 0; reg < 4; ++reg)
                    v[reg] = fmaxf(acc[rr][mt][reg] + bptr[16 * mt + 4 * slot + reg], 0.f);
                *(uint2*)(outP + off) = make_uint2(pack2(v[0], v[1]), pack2(v[2], v[3]));
            }
        }
    }
}

// ---------------------------------------------------------------------------
// Pipelined double-buffered DMA conv on padded NHWC bf16 (8 tiles/block).
// ---------------------------------------------------------------------------
template<int EPI>
__global__ __launch_bounds__(TPB) void dconv64p_k(
    const ushortT* __restrict__ inP0, const short* __restrict__ wbase, int wstr,
    ushortT* __restrict__ outP0,
    const float* __restrict__ gamma0, const float* __restrict__ beta0,
    const float* __restrict__ xorig0, float* __restrict__ outE0, float* __restrict__ outM0)
{
    constexpr int MT = (EPI == 3) ? 1 : 2;
    constexpr int RSX = 66;
    constexpr int ROWB = RSX * 64;
    constexpr int BUFB = 6 * RSX * 64;
    __shared__ s16x8 lds_t[2 * 6 * RSX * 4];
    char* sbase = (char*)lds_t;

    const int z = blockIdx.z;
    const ushortT* inP = inP0 + (size_t)z * PSTR;
    const short* wslot = wbase + (size_t)z * wstr;

    const int tid = threadIdx.x, lane = tid & 63, wv = tid >> 6;
    const int bid = blockIdx.x;                 // 0..127
    const int xcd = bid & 7, idx = bid >> 3;    // idx 0..15
    const int x0 = (idx & 7) * 64;
    const int yband = xcd * 2 + (idx >> 3);     // 0..15, 32 rows each
    const int l15 = lane & 15, slot = lane >> 4;

    s16x8 wf[9][MT];
    #pragma unroll
    for (int t = 0; t < 9; ++t)
        #pragma unroll
        for (int mt = 0; mt < MT; ++mt)
            wf[t][mt] = *(const s16x8*)(wslot + ((size_t)(t * 2 + mt) * 64 + lane) * 8);

    const int xw = 16 * wv;
    int roff[3];
    #pragma unroll
    for (int dx = 0; dx < 3; ++dx) {
        const int lx = xw + dx + l15;
        const int vs = (lx + (lx >> 2)) & 3;
        roff[dx] = lx * 64 + ((slot ^ vs) << 4);
    }
    const float* bptr = (const float*)(wslot + 9216);

    auto stage = [&](int t, int b) {
        const int y0 = yband * 32 + 4 * t;
        char* sb = sbase + b * BUFB;
        #pragma unroll
        for (int j = 0; j < 6; ++j) {
            const int p = j * 256 + tid;
            const int row = p / 264;
            const int rem = p - row * 264;
            const int lx = rem >> 2, osl = rem & 3;
            const int o = osl ^ ((lx + (lx >> 2)) & 3);
            const ushortT* gp = inP + ((size_t)(y0 + row) * 514 + x0 + lx) * 32 + o * 8;
            GLOAD_LDS16(gp, sb + (size_t)(j * 256 + wv * 64) * 16);
        }
        if (tid < 48) {
            const int p = 1536 + tid;
            const int row = p / 264;
            const int rem = p - row * 264;
            const int lx = rem >> 2, osl = rem & 3;
            const int o = osl ^ ((lx + (lx >> 2)) & 3);
            const ushortT* gp = inP + ((size_t)(y0 + row) * 514 + x0 + lx) * 32 + o * 8;
            GLOAD_LDS16(gp, sb + (size_t)1536 * 16);
        }
    };

    stage(0, 0);

    #pragma unroll 1
    for (int t = 0; t < 8; ++t) {
        __syncthreads();
        if (t < 7) stage(t + 1, (t + 1) & 1);
        char* sb = sbase + (t & 1) * BUFB;
        const int y0t = yband * 32 + 4 * t;

        #pragma unroll
        for (int r2 = 0; r2 < 4; r2 += 2) {
            f32x4 acc[2][MT];
            #pragma unroll
            for (int a = 0; a < 2; ++a)
                #pragma unroll
                for (int b = 0; b < MT; ++b)
                    #pragma unroll
                    for (int e = 0; e < 4; ++e) acc[a][b][e] = 0.f;

            #pragma unroll
            for (int dy = 0; dy < 3; ++dy) {
                const int rb0 = (r2 + dy) * ROWB;
                #pragma unroll
                for (int dx = 0; dx < 3; ++dx) {
                    const int tap = dy * 3 + dx;
                    const s16x8 b0 = *(const s16x8*)(sb + rb0 + roff[dx]);
                    const s16x8 b1 = *(const s16x8*)(sb + rb0 + ROWB + roff[dx]);
                    #pragma unroll
                    for (int mt = 0; mt < MT; ++mt) {
                        acc[0][mt] = __builtin_amdgcn_mfma_f32_16x16x32_bf16(wf[tap][mt], b0, acc[0][mt], 0, 0, 0);
                        acc[1][mt] = __builtin_amdgcn_mfma_f32_16x16x32_bf16(wf[tap][mt], b1, acc[1][mt], 0, 0, 0);
                    }
                }
            }

            #pragma unroll
            for (int rr = 0; rr < 2; ++rr) {
                const int gy = y0t + r2 + rr;
                const int gx = x0 + xw + l15;
                if constexpr (EPI == 3) {
                    if (slot == 0) {
                        const float* xorig = xorig0 + (size_t)z * 3 * HW;
                        float* outE = outE0 + (size_t)z * 3 * HW;
                        float* outM = outM0 + (size_t)z * HW;
                        const float om = tanhf(acc[rr][0][0] + bptr[0]);
                        outM[(size_t)gy * 512 + gx] = om;
                        #pragma unroll
                        for (int c = 0; c < 3; ++c) {
                            const size_t xi = ((size_t)c * 512 + gy) * 512 + gx;
                            const float xv = xorig[xi];
                            outE[xi] = xv + om * (xv * xv - xv);
                        }
                    }
                } else {
                    ushortT* outP = outP0 + (size_t)z * PSTR;
                    #pragma unroll
                    for (int mt = 0; mt < MT; ++mt) {
                        const size_t off = ((size_t)(gy + 1) * 514 + gx + 1) * 32 + 16 * mt + 4 * slot;
                        float v[4];
                        #pragma unroll
                        for (int reg = 0; reg < 4; ++reg)
                            v[reg] = acc[rr][mt][reg] + bptr[16 * mt + 4 * slot + reg];
                        if constexpr (EPI == 0) {
                            #pragma unroll
                            for (int reg = 0; reg < 4; ++reg) v[reg] = fmaxf(v[reg], 0.f);
                        } else if constexpr (EPI == 2) {
                            const int prow = r2 + rr + 1;
                            const int lxr = xw + l15 + 1;
                            const int vsr = (lxr + (lxr >> 2)) & 3;
                            const int oo = (2 * mt + (slot >> 1)) ^ vsr;
                            const uint2 din = *(const uint2*)(sb + (prow * RSX + lxr) * 64 + (oo << 4) + ((slot & 1) << 3));
                            const float* gamma = gamma0 + 32 * z;
                            const float* beta  = beta0 + 32 * z;
                            const int cb = 16 * mt + 4 * slot;
                            v[0] = bf2f((unsigned short)(din.x & 0xffff)) + gamma[cb + 0] * v[0] + beta[cb + 0];
                            v[1] = bf2f((unsigned short)(din.x >> 16))    + gamma[cb + 1] * v[1] + beta[cb + 1];
                            v[2] = bf2f((unsigned short)(din.y & 0xffff)) + gamma[cb + 2] * v[2] + beta[cb + 2];
                            v[3] = bf2f((unsigned short)(din.y >> 16))    + gamma[cb + 3] * v[3] + beta[cb + 3];
                        }
                        *(uint2*)(outP + off) = make_uint2(pack2(v[0], v[1]), pack2(v[2], v[3]));
                    }
                }
            }
        }
    }
}

// ---------------------------------------------------------------------------
extern "C" void kernel_launch(void* const* d_in, const int* in_sizes, int n_in,
                              void* d_out, int out_size, void* d_ws, size_t ws_size,
                              hipStream_t stream)
{
    const float* x      = (const float*)d_in[0];
    const float* cdc_w  = (const float*)d_in[11];
    const float* t1_w   = (const float*)d_in[14];
    const float* t1_b   = (const float*)d_in[15];
    const float* t2_w   = (const float*)d_in[16];
    const float* t2_b   = (const float*)d_in[17];
    const float* t3_w   = (const float*)d_in[18];
    const float* t3_b   = (const float*)d_in[19];
    const float* fc1_w  = (const float*)d_in[22];
    const float* fc1_b  = (const float*)d_in[23];
    const float* fc2_w  = (const float*)d_in[24];
    const float* fc2_b  = (const float*)d_in[25];
    const float* fc3_w  = (const float*)d_in[26];
    const float* fc3_b  = (const float*)d_in[27];
    const float* g_w    = (const float*)d_in[28];
    const float* g_b    = (const float*)d_in[29];
    const float* be_w   = (const float*)d_in[30];
    const float* be_b   = (const float*)d_in[31];

    float* out = (float*)d_out;

    // workspace layout
    ushortT* A2 = (ushortT*)d_ws;                  // 4 x 16.9 MB
    ushortT* B2 = A2 + 4 * PSTR;                   // 4 x 16.9 MB
    float* part  = (float*)(B2 + 4 * PSTR);        // 131072
    float* am0   = part + 131072;                  // 256
    float* am1   = am0 + 256;                      // 2048
    float* am2   = am1 + 2048;
    float* am3   = am2 + 2048;
    float* theta = am3 + 2048;                     // 4
    float* gamma = theta + 4;                      // 128 [4][32]
    float* beta  = gamma + 128;                    // 128
    short* wpack = (short*)(beta + 128);           // 16 x 10240 shorts
    const size_t need_bytes = (size_t)((char*)(wpack + 16 * 10240) - (char*)d_ws);
    if (ws_size < need_bytes) return;

    const dim3 blk(TPB);

    // --- phase A ---
    packall_k<<<dim3(12), dim3(64), 0, stream>>>(
        (const float*)d_in[1], (const float*)d_in[2], (const float*)d_in[3], (const float*)d_in[4],
        (const float*)d_in[5], (const float*)d_in[6], (const float*)d_in[7], (const float*)d_in[8],
        (const float*)d_in[9], (const float*)d_in[10], (const float*)d_in[32], (const float*)d_in[33],
        (const float*)d_in[34], (const float*)d_in[35], (const float*)d_in[36], (const float*)d_in[37],
        (const float*)d_in[12], (const float*)d_in[13], (const float*)d_in[20], (const float*)d_in[21],
        wpack);

    zero_k<<<dim3((8 * 32832 + TPB - 1) / TPB), blk, 0, stream>>>((unsigned int*)A2, (unsigned int*)B2);

    ctlf_k<<<dim3(256, 4, 4), blk, 0, stream>>>(x, wpack + 8 * 10240, part);

    // fused means + t-chain; then parallel FC chain; gamma/beta; cdc pack
    meantch_k<<<dim3(4), blk, 0, stream>>>(part, t1_w, t1_b, t2_w, t2_b, t3_w, t3_b, am0, theta);
    fcw_k<0><<<dim3(512), blk, 0, stream>>>(am0, fc1_w, fc1_b, am1, 64, 512);
    fcw_k<0><<<dim3(512), blk, 0, stream>>>(am1, fc2_w, fc2_b, am2, 512, 512);
    fcw_k<1><<<dim3(512), blk, 0, stream>>>(am2, fc3_w, fc3_b, am3, 512, 512);
    gb_k<<<dim3(64), blk, 0, stream>>>(am3, g_w, g_b, be_w, be_b, gamma, beta);
    packcdc_k<<<dim3(4), dim3(64), 0, stream>>>(cdc_w, theta, wpack);

    // --- heavy chain: enc1n + 8 pipelined dconv64p dispatches (8 tiles/blk) ---
    const dim3 gE(1024, 1, 4);
    const dim3 gP(128, 1, 4);
    float* outM = out + (size_t)4 * 3 * HW;

    enc1n_k<<<gE, blk, 0, stream>>>(x, wpack, A2);
    dconv64p_k<0><<<gP, blk, 0, stream>>>(A2, wpack + 1 * 10240, 0, B2, nullptr, nullptr, nullptr, nullptr, nullptr);
    dconv64p_k<0><<<gP, blk, 0, stream>>>(B2, wpack + 2 * 10240, 0, A2, nullptr, nullptr, nullptr, nullptr, nullptr);
    dconv64p_k<0><<<gP, blk, 0, stream>>>(A2, wpack + 3 * 10240, 0, B2, nullptr, nullptr, nullptr, nullptr, nullptr);
    dconv64p_k<0><<<gP, blk, 0, stream>>>(B2, wpack + 4 * 10240, 0, A2, nullptr, nullptr, nullptr, nullptr, nullptr);
    // cdc (theta folded per batch): A2 -> B2 = f_deco
    dconv64p_k<0><<<gP, blk, 0, stream>>>(A2, wpack + 12 * 10240, 10240, B2, nullptr, nullptr, nullptr, nullptr, nullptr);
    // res: B2 -> A2 (residual from LDS)
    dconv64p_k<2><<<gP, blk, 0, stream>>>(B2, wpack + 5 * 10240, 0, A2, gamma, beta, nullptr, nullptr, nullptr);
    // d1: A2 -> B2
    dconv64p_k<0><<<gP, blk, 0, stream>>>(A2, wpack + 6 * 10240, 0, B2, nullptr, nullptr, nullptr, nullptr, nullptr);
    // d2 + tanh + enhance -> outputs
    dconv64p_k<3><<<gP, blk, 0, stream>>>(B2, wpack + 7 * 10240, 0, nullptr, nullptr, nullptr, x, out, outM);
}